// Round 3
// baseline (403.034 us; speedup 1.0000x reference)
//
#include <hip/hip_runtime.h>

// ToRGBLayer: style affine + 1x1 modulated conv (demod=false) + bias + clip + residual
//
// Shapes (fixed by reference):
//   x        [8, 128, 128, 512] f32
//   y        [8, 128, 128, 3]   f32
//   dlatents [8, 18, 512]       f32   (use layer 17)
//   affine_w [512, 512]         f32
//   affine_b [512]              f32
//   conv_w   [1, 1, 512, 3]     f32
//   conv_b   [3]                f32
//   out      [8, 128, 128, 3]   f32

#define NB      8
#define NUM_WS  18
#define LIDX    17
#define WD      512
#define CI      512
#define FM      3
#define HW      16384      // 128*128
#define CLIPV   256.0f
#define PIX_PER_WAVE 8

// ---------------- K1: per-image folded weights weff[n][c] = {s*cw0, s*cw1, s*cw2, 0} ---------
__global__ __launch_bounds__(512) void k_style(
    const float* __restrict__ dlat,   // [NB, NUM_WS, WD]
    const float* __restrict__ aw,     // [WD, CI]
    const float* __restrict__ ab,     // [CI]
    const float* __restrict__ cw,     // [CI, FM]  (k=1)
    float4* __restrict__ weff)        // [NB, CI]
{
    const int n = blockIdx.x;
    const int c = threadIdx.x;
    const float* __restrict__ d = dlat + ((size_t)n * NUM_WS + LIDX) * WD;
    float s = 0.f;
    #pragma unroll 8
    for (int w = 0; w < WD; ++w)
        s = fmaf(d[w], aw[(size_t)w * CI + c], s);   // aw column read: coalesced across threads
    const float inv = 0.04419417382415922f;          // 1/sqrt(512) — both he_std factors
    s = s * inv + ab[c];                             // style (LR_MULT = 1)
    const float ws = s * inv;                        // fold conv he_std
    weff[n * CI + c] = make_float4(ws * cw[c * FM + 0],
                                   ws * cw[c * FM + 1],
                                   ws * cw[c * FM + 2],
                                   0.f);
}

// ---------------- K2: wave-per-pixel 512->3 dot, weights in registers ------------------------
__global__ __launch_bounds__(256) void k_conv(
    const float* __restrict__ x,      // [NB, HW, CI]
    const float* __restrict__ y,      // [NB, HW, FM]
    const float4* __restrict__ weff,  // [NB, CI]
    const float* __restrict__ cb,     // [FM]
    float* __restrict__ out)          // [NB, HW, FM]
{
    const int n    = blockIdx.y;
    const int wave = threadIdx.x >> 6;
    const int lane = threadIdx.x & 63;
    const int c0   = lane * 8;

    // Hoist this lane's 8 channels x 3 fmaps of weights into registers (reused for all pixels).
    const float4* __restrict__ wp = weff + n * CI + c0;
    float w0[8], w1[8], w2[8];
    #pragma unroll
    for (int j = 0; j < 8; ++j) {
        float4 w = wp[j];
        w0[j] = w.x; w1[j] = w.y; w2[j] = w.z;
    }
    const float b0 = cb[0], b1 = cb[1], b2 = cb[2];

    const int pix0 = (blockIdx.x * 4 + wave) * PIX_PER_WAVE;
    const float* __restrict__ xb = x + (size_t)n * HW * CI;

    for (int i = 0; i < PIX_PER_WAVE; ++i) {
        const int pix = pix0 + i;
        const float4* __restrict__ xp = (const float4*)(xb + (size_t)pix * CI + c0);
        float4 xa = xp[0];
        float4 xc = xp[1];
        float xv[8] = {xa.x, xa.y, xa.z, xa.w, xc.x, xc.y, xc.z, xc.w};
        float a0 = 0.f, a1 = 0.f, a2 = 0.f;
        #pragma unroll
        for (int j = 0; j < 8; ++j) {
            a0 = fmaf(xv[j], w0[j], a0);
            a1 = fmaf(xv[j], w1[j], a1);
            a2 = fmaf(xv[j], w2[j], a2);
        }
        // 64-lane butterfly: all lanes end with the full sums
        #pragma unroll
        for (int m = 1; m < 64; m <<= 1) {
            a0 += __shfl_xor(a0, m, 64);
            a1 += __shfl_xor(a1, m, 64);
            a2 += __shfl_xor(a2, m, 64);
        }
        if (lane < 3) {
            float a = (lane == 0) ? a0 : (lane == 1 ? a1 : a2);
            float b = (lane == 0) ? b0 : (lane == 1 ? b1 : b2);
            const size_t ob = ((size_t)n * HW + pix) * FM + lane;
            out[ob] = fminf(fmaxf(a + b, -CLIPV), CLIPV) + y[ob];
        }
    }
}

extern "C" void kernel_launch(void* const* d_in, const int* in_sizes, int n_in,
                              void* d_out, int out_size, void* d_ws, size_t ws_size,
                              hipStream_t stream) {
    const float* x    = (const float*)d_in[0];
    const float* y    = (const float*)d_in[1];
    const float* dlat = (const float*)d_in[2];
    const float* aw   = (const float*)d_in[3];
    const float* ab   = (const float*)d_in[4];
    const float* cw   = (const float*)d_in[5];
    const float* cb   = (const float*)d_in[6];
    float* out = (float*)d_out;
    float4* weff = (float4*)d_ws;     // NB*CI float4 = 32 KiB

    k_style<<<dim3(NB), dim3(512), 0, stream>>>(dlat, aw, ab, cw, weff);

    // HW / (4 waves * PIX_PER_WAVE) blocks per image
    const int blocks_x = HW / (4 * PIX_PER_WAVE);   // 512
    k_conv<<<dim3(blocks_x, NB), dim3(256), 0, stream>>>(x, y, weff, cb, out);
}

// Round 4
// 386.343 us; speedup vs baseline: 1.0432x; 1.0432x over previous
//
#include <hip/hip_runtime.h>

// ToRGBLayer: style affine + 1x1 modulated conv (demod=false) + bias + clip + residual
//
// Shapes (fixed by reference):
//   x        [8, 128, 128, 512] f32
//   y        [8, 128, 128, 3]   f32
//   dlatents [8, 18, 512]       f32   (use layer 17)
//   affine_w [512, 512]         f32
//   affine_b [512]              f32
//   conv_w   [1, 1, 512, 3]     f32
//   conv_b   [3]                f32
//   out      [8, 128, 128, 3]   f32

#define NB      8
#define NUM_WS  18
#define LIDX    17
#define WD      512
#define CI      512
#define FM      3
#define HW      16384      // 128*128
#define CLIPV   256.0f
#define PIX     16         // pixels per wave

// ---------------- K1: per-image folded weights weff[n][c] = {s*cw0, s*cw1, s*cw2, 0} ---------
__global__ __launch_bounds__(512) void k_style(
    const float* __restrict__ dlat,   // [NB, NUM_WS, WD]
    const float* __restrict__ aw,     // [WD, CI]
    const float* __restrict__ ab,     // [CI]
    const float* __restrict__ cw,     // [CI, FM]  (k=1)
    float4* __restrict__ weff)        // [NB, CI]
{
    const int n = blockIdx.x;
    const int c = threadIdx.x;
    const float* __restrict__ d = dlat + ((size_t)n * NUM_WS + LIDX) * WD;
    float s = 0.f;
    #pragma unroll 16
    for (int w = 0; w < WD; ++w)
        s = fmaf(d[w], aw[(size_t)w * CI + c], s);   // aw column read: coalesced across threads
    const float inv = 0.04419417382415922f;          // 1/sqrt(512) — both he_std factors
    s = s * inv + ab[c];                             // style (LR_MULT = 1)
    const float ws = s * inv;                        // fold conv he_std
    weff[n * CI + c] = make_float4(ws * cw[c * FM + 0],
                                   ws * cw[c * FM + 1],
                                   ws * cw[c * FM + 2],
                                   0.f);
}

// ---------------- K2: wave-per-pixel 512->3 dot, weights in registers, 2-stage pipeline ------
__global__ __launch_bounds__(256) void k_conv(
    const float* __restrict__ x,      // [NB, HW, CI]
    const float* __restrict__ y,      // [NB, HW, FM]
    const float4* __restrict__ weff,  // [NB, CI]
    const float* __restrict__ cb,     // [FM]
    float* __restrict__ out)          // [NB, HW, FM]
{
    const int n    = blockIdx.y;
    const int wave = threadIdx.x >> 6;
    const int lane = threadIdx.x & 63;
    const int c0   = lane * 8;

    // Hoist this lane's 8 channels x 3 fmaps of weights into registers (reused for all pixels).
    const float4* __restrict__ wp = weff + n * CI + c0;
    float w0[8], w1[8], w2[8];
    #pragma unroll
    for (int j = 0; j < 8; ++j) {
        float4 w = wp[j];
        w0[j] = w.x; w1[j] = w.y; w2[j] = w.z;
    }
    const float b0 = cb[0], b1 = cb[1], b2 = cb[2];

    const int pix0 = (blockIdx.x * 4 + wave) * PIX;
    // lane's slice of pixel pix0+i lives at xq[i*128] / xq[i*128+1]  (CI/4 = 128 float4 per pixel)
    const float4* __restrict__ xq =
        (const float4*)(x + ((size_t)n * HW + pix0) * CI + c0);

    // software pipeline: prefetch pixel i+1 before the dependent chain of pixel i
    float4 na = xq[0];
    float4 nc = xq[1];
    float res = 0.f;   // lane 3i+f collects pixel i, fmap f

    #pragma unroll
    for (int i = 0; i < PIX; ++i) {
        float4 xa = na, xc = nc;
        if (i + 1 < PIX) {
            na = xq[(i + 1) * 128];
            nc = xq[(i + 1) * 128 + 1];
        }
        float xv[8] = {xa.x, xa.y, xa.z, xa.w, xc.x, xc.y, xc.z, xc.w};
        float a0 = 0.f, a1 = 0.f, a2 = 0.f;
        #pragma unroll
        for (int j = 0; j < 8; ++j) {
            a0 = fmaf(xv[j], w0[j], a0);
            a1 = fmaf(xv[j], w1[j], a1);
            a2 = fmaf(xv[j], w2[j], a2);
        }
        // 64-lane butterfly: ALL lanes end with the full sums
        #pragma unroll
        for (int m = 1; m < 64; m <<= 1) {
            a0 += __shfl_xor(a0, m, 64);
            a1 += __shfl_xor(a1, m, 64);
            a2 += __shfl_xor(a2, m, 64);
        }
        const int idx = lane - 3 * i;
        if (idx >= 0 && idx < 3)
            res = (idx == 0) ? a0 + b0 : (idx == 1 ? a1 + b1 : a2 + b2);
    }

    // coalesced epilogue: lanes 0..47 hold the 16 pixels x 3 fmaps in linear order
    if (lane < 3 * PIX) {
        const size_t ob = ((size_t)n * HW + pix0) * FM + lane;
        out[ob] = fminf(fmaxf(res, -CLIPV), CLIPV) + y[ob];
    }
}

extern "C" void kernel_launch(void* const* d_in, const int* in_sizes, int n_in,
                              void* d_out, int out_size, void* d_ws, size_t ws_size,
                              hipStream_t stream) {
    const float* x    = (const float*)d_in[0];
    const float* y    = (const float*)d_in[1];
    const float* dlat = (const float*)d_in[2];
    const float* aw   = (const float*)d_in[3];
    const float* ab   = (const float*)d_in[4];
    const float* cw   = (const float*)d_in[5];
    const float* cb   = (const float*)d_in[6];
    float* out = (float*)d_out;
    float4* weff = (float4*)d_ws;     // NB*CI float4 = 32 KiB

    k_style<<<dim3(NB), dim3(512), 0, stream>>>(dlat, aw, ab, cw, weff);

    // HW / (4 waves * PIX) = 256 blocks per image -> 2048 blocks, 8192 waves (full residency)
    const int blocks_x = HW / (4 * PIX);
    k_conv<<<dim3(blocks_x, NB), dim3(256), 0, stream>>>(x, y, weff, cb, out);
}

// Round 5
// 380.973 us; speedup vs baseline: 1.0579x; 1.0141x over previous
//
#include <hip/hip_runtime.h>

// ToRGBLayer: style affine + 1x1 modulated conv (demod=false) + bias + clip + residual
//
//   x        [8, 128, 128, 512] f32     (268 MB — the only traffic that matters)
//   y        [8, 128, 128, 3]   f32
//   dlatents [8, 18, 512]       f32     (layer 17)
//   affine_w [512, 512] f32, affine_b [512] f32
//   conv_w   [1,1,512,3] f32, conv_b [3] f32
//   out      [8, 128, 128, 3]   f32

#define NB      8
#define NUM_WS  18
#define LIDX    17
#define WD      512
#define CI      512
#define FM      3
#define HW      16384
#define CLIPV   256.0f
#define PIX     16         // pixels per wave

// ---------------- K1: per-image folded weights weff[n][c] = {s*cw0, s*cw1, s*cw2, 0} ---------
__global__ __launch_bounds__(512) void k_style(
    const float* __restrict__ dlat,
    const float* __restrict__ aw,
    const float* __restrict__ ab,
    const float* __restrict__ cw,
    float4* __restrict__ weff)
{
    const int n = blockIdx.x;
    const int c = threadIdx.x;
    const float* __restrict__ d = dlat + ((size_t)n * NUM_WS + LIDX) * WD;
    float s = 0.f;
    #pragma unroll 16
    for (int w = 0; w < WD; ++w)
        s = fmaf(d[w], aw[(size_t)w * CI + c], s);
    const float inv = 0.04419417382415922f;          // 1/sqrt(512)
    s = s * inv + ab[c];
    const float ws = s * inv;
    weff[n * CI + c] = make_float4(ws * cw[c * FM + 0],
                                   ws * cw[c * FM + 1],
                                   ws * cw[c * FM + 2],
                                   0.f);
}

// DPP row_ror fold: a += rotate-within-16-lane-row(a, N).  VALU-only, no DS pipe.
template <int CTRL>
__device__ __forceinline__ float dpp_fold(float a) {
    int v = __builtin_amdgcn_mov_dpp(__float_as_int(a), CTRL, 0xF, 0xF, true);
    return a + __int_as_float(v);
}
#define ROR8 0x128
#define ROR4 0x124
#define ROR2 0x122
#define ROR1 0x121

// ---------------- K2: wave-per-pixel 512->3 dot; DPP row-sums + LDS mini-transpose -----------
__global__ __launch_bounds__(256) void k_conv(
    const float* __restrict__ x,      // [NB, HW, CI]
    const float* __restrict__ y,      // [NB, HW, FM]
    const float4* __restrict__ weff,  // [NB, CI]
    const float* __restrict__ cb,     // [FM]
    float* __restrict__ out)          // [NB, HW, FM]
{
    __shared__ float sm[4 * PIX * FM * 4];   // [wave][pix][fmap][row] = 3 KB

    const int n    = blockIdx.y;
    const int wave = threadIdx.x >> 6;
    const int lane = threadIdx.x & 63;
    const int row  = lane >> 4;              // 16-lane row (4 rows/wave)
    const int t    = lane & 15;
    const int c0   = lane * 8;

    // this lane's 8 channels x 3 fmaps of folded weights, hoisted to registers
    const float4* __restrict__ wp = weff + n * CI + c0;
    float w0[8], w1[8], w2[8];
    #pragma unroll
    for (int j = 0; j < 8; ++j) {
        float4 w = wp[j];
        w0[j] = w.x; w1[j] = w.y; w2[j] = w.z;
    }

    const int pix0 = (blockIdx.x * 4 + wave) * PIX;
    const float4* __restrict__ xq =
        (const float4*)(x + ((size_t)n * HW + pix0) * CI + c0);   // stride 128 float4/pixel

    // depth-2 prefetch ring (indices become compile-time constants under full unroll)
    float4 pa[2], pc[2];
    pa[0] = xq[0];       pc[0] = xq[1];
    pa[1] = xq[128];     pc[1] = xq[129];

    #pragma unroll
    for (int i = 0; i < PIX; ++i) {
        const float4 xa = pa[i & 1];
        const float4 xc = pc[i & 1];
        if (i + 2 < PIX) {
            pa[i & 1] = xq[(i + 2) * 128];
            pc[i & 1] = xq[(i + 2) * 128 + 1];
        }
        const float xv[8] = {xa.x, xa.y, xa.z, xa.w, xc.x, xc.y, xc.z, xc.w};
        float a0 = 0.f, a1 = 0.f, a2 = 0.f;
        #pragma unroll
        for (int j = 0; j < 8; ++j) {
            a0 = fmaf(xv[j], w0[j], a0);
            a1 = fmaf(xv[j], w1[j], a1);
            a2 = fmaf(xv[j], w2[j], a2);
        }
        // 16-lane row reduction, pure VALU DPP (3 independent 4-deep chains)
        a0 = dpp_fold<ROR8>(a0); a1 = dpp_fold<ROR8>(a1); a2 = dpp_fold<ROR8>(a2);
        a0 = dpp_fold<ROR4>(a0); a1 = dpp_fold<ROR4>(a1); a2 = dpp_fold<ROR4>(a2);
        a0 = dpp_fold<ROR2>(a0); a1 = dpp_fold<ROR2>(a1); a2 = dpp_fold<ROR2>(a2);
        a0 = dpp_fold<ROR1>(a0); a1 = dpp_fold<ROR1>(a1); a2 = dpp_fold<ROR1>(a2);
        // deposit 12 row-partials (pix, fmap, row); banks 0..11+offset -> conflict-free
        if (t < FM) {
            const float v = (t == 0) ? a0 : (t == 1 ? a1 : a2);
            sm[((wave * PIX + i) * FM + t) * 4 + row] = v;   // fire-and-forget
        }
    }

    // per-wave epilogue (own LDS region only — no barrier needed):
    // lane < 48 handles (pix = lane/3, fmap = lane%3); output index is exactly lane.
    if (lane < FM * PIX) {
        const float4 p = *(const float4*)&sm[(wave * PIX * FM + lane) * 4];
        const int f = lane - 3 * (lane / 3);
        const float bias = (f == 0) ? cb[0] : (f == 1 ? cb[1] : cb[2]);
        const float s = (p.x + p.y) + (p.z + p.w) + bias;
        const size_t ob = ((size_t)n * HW + pix0) * FM + lane;
        out[ob] = fminf(fmaxf(s, -CLIPV), CLIPV) + y[ob];
    }
}

extern "C" void kernel_launch(void* const* d_in, const int* in_sizes, int n_in,
                              void* d_out, int out_size, void* d_ws, size_t ws_size,
                              hipStream_t stream) {
    const float* x    = (const float*)d_in[0];
    const float* y    = (const float*)d_in[1];
    const float* dlat = (const float*)d_in[2];
    const float* aw   = (const float*)d_in[3];
    const float* ab   = (const float*)d_in[4];
    const float* cw   = (const float*)d_in[5];
    const float* cb   = (const float*)d_in[6];
    float* out = (float*)d_out;
    float4* weff = (float4*)d_ws;     // NB*CI float4 = 32 KiB

    k_style<<<dim3(NB), dim3(512), 0, stream>>>(dlat, aw, ab, cw, weff);

    // HW / (4 waves * PIX) = 256 blocks per image -> 2048 blocks, 8192 waves (full residency)
    const int blocks_x = HW / (4 * PIX);
    k_conv<<<dim3(blocks_x, NB), dim3(256), 0, stream>>>(x, y, weff, cb, out);
}